// Round 8
// baseline (406.830 us; speedup 1.0000x reference)
//
#include <hip/hip_runtime.h>
#include <stdint.h>

// ClassicalHopfield N=8192, P=64.  act_i·N = x_i·m - 64·s_i, m = X^T s (running).
// Blocked (64-neuron) sequential resolve; corrections via 64-bit sign
// signatures (y = s⊙x ∈ {±1}^64):
//   flip i:    ΔU_j = 8·popc(sig_i^sig_j) - 256            (= -2·y_j·y_i scaled)
//   block end: m_p += 4·popc(flips & sigT_p) - 2·nf
// U_j = 2·(y_j·m) - (s_j<0) - 128 - 256·nf_sofar, flip ⟺ U_j < 0. The -(s<0)
// implements act==0 -> +1 exactly. All small integers => exact => bit-identical.
//
// Round-8 == Round-7 resubmit (R7 hit GPUAcquisitionTimeout, never measured).
// 2-wide SPECULATIVE resolve: measured per-flip cost ~160cy comes from
// VALU<->SALU crossings (vcc/SGPR interlocks), not instruction count.
// Per iteration: pick first TWO candidates of mm, readlane both sigs in one
// hazard window, apply both corrections, verify speculation (i2 still first
// candidate after i1's correction) OFF the critical path; ~95%+ commit rate.
// Fallback costs 2 instrs and reuses the verify mask. thr folded into U.

#define NB 128
typedef unsigned long long u64;
typedef unsigned u32;

// ws: m0 f[64] | Ysw f[128*4096] (pre-swizzled, glds-linear layout:
//     [b][j][ (G^(j&7))*4 + c ], p=G*4+c) | sig u64[8192] | sigT u64[8192] |
//     sps f[8192]   ~2.16 MB

__device__ __forceinline__ void glds16(const void* g, void* l) {
  __builtin_amdgcn_global_load_lds(
      (const __attribute__((address_space(1))) void*)g,
      (__attribute__((address_space(3))) void*)l, 16, 0, 0);
}

__global__ __launch_bounds__(256) void hop_prep(
    const float* __restrict__ X, const float* __restrict__ state,
    const int* __restrict__ perm, float* __restrict__ m0,
    float* __restrict__ Ysw, u64* __restrict__ sig, u64* __restrict__ sigT,
    float* __restrict__ sps)
{
  const int b = blockIdx.x, t = threadIdx.x;
  const int wv = t >> 6, ln = t & 63;
  __shared__ u64 sigL[64];
  __shared__ float red[4][64];

  // single X pass: swizzled Y store + row signature + m0 partial
  float acc = 0.f;
  #pragma unroll
  for (int jj = 0; jj < 16; ++jj) {
    const int j = wv*16 + jj;                 // wave-uniform row
    const int r = perm[b*64 + j];
    const float sr = state[r];
    const float x = X[(size_t)r*64 + ln];     // coalesced 256B row
    Ysw[(size_t)b*4096 + j*64 + ((((ln >> 2) ^ (j & 7)) << 2) | (ln & 3))] = x * sr;
    u64 bb = __ballot(x < 0.f);
    if (sr < 0.f) bb = ~bb;                   // sign of y = x*sr
    if (ln == 0) { sig[b*64 + j] = bb; sigL[j] = bb; }
    acc = fmaf(x, sr, acc);
  }
  red[wv][ln] = acc;
  __syncthreads();

  // column signatures: bit i of sigT_p = bit p of sig_i
  {
    const u64 gs = sigL[ln];
    #pragma unroll
    for (int jj = 0; jj < 16; ++jj) {
      const int p = wv*16 + jj;
      u64 tb = __ballot((unsigned)((gs >> p) & 1ull));
      if (ln == 0) sigT[b*64 + p] = tb;
    }
  }

  if (t < 64) {
    atomicAdd(&m0[t], (red[0][t] + red[1][t]) + (red[2][t] + red[3][t]));
    sps[b*64 + t] = state[perm[b*64 + t]];
  }
}

// One 64-neuron block: LDS matvec -> U margins -> 2-wide speculative resolve.
#define PROCESS(YB, sg, st, rr, ss) {                                         \
  const float* Yc = (YB);                                                     \
  float q0=0.f,q1=0.f,q2=0.f,q3=0.f;                                          \
  const float4* mv4 = (const float4*)mlds;                                    \
  _Pragma("unroll")                                                           \
  for (int g = 0; g < 16; ++g) {                                              \
    const float4 yv = *(const float4*)&Yc[ybase + ((g ^ lswz) << 2)];         \
    const float4 mv = mv4[g];                                                 \
    q0 = fmaf(yv.x, mv.x, q0); q1 = fmaf(yv.y, mv.y, q1);                     \
    q2 = fmaf(yv.z, mv.z, q2); q3 = fmaf(yv.w, mv.w, q3);                     \
  }                                                                           \
  int U = (((int)((q0+q1)+(q2+q3))) << 1) - (((ss) < 0.f) ? 1 : 0) - 128;     \
  const u32 slo = (u32)(sg), shi = (u32)((sg) >> 32);                         \
  u64 flips;                                                                  \
  {                                                                           \
    u64 mm, t_, mm1, l1, b1;                                                  \
    u32 i1, i2, i2s, chk, tmp, ra0, ra1, rb0, rb1;                            \
    int U1; u32 va0, va1, vb0, vb1, ca, cb;                                   \
    asm volatile(                                                             \
      "s_mov_b64 %[flips], 0\n\t"                                             \
      "v_cmp_gt_i32 vcc, 0, %[U]\n\t"                                         \
      "s_and_b64 %[mm], vcc, vcc\n\t"        /* mm = vcc, SCC = (mm!=0) */    \
      "s_cbranch_scc0 9f\n\t"                                                 \
      "1:\n\t"                                                                \
      "s_ff1_i32_b64 %[i1], %[mm]\n\t"                                        \
      "s_lshl_b64 %[b1], 1, %[i1]\n\t"                                        \
      "s_andn2_b64 %[t], %[mm], %[b1]\n\t"                                    \
      "s_or_b64 %[flips], %[flips], %[b1]\n\t"                                \
      "s_ff1_i32_b64 %[i2], %[t]\n\t"        /* -1 if no 2nd candidate */     \
      "s_cmp_lg_u64 %[t], 0\n\t"                                              \
      "s_cselect_b32 %[i2s], %[i2], %[i1]\n\t"                                \
      "v_readlane_b32 %[ra0], %[slo], %[i1]\n\t"                              \
      "v_readlane_b32 %[ra1], %[shi], %[i1]\n\t"                              \
      "v_readlane_b32 %[rb0], %[slo], %[i2s]\n\t"                             \
      "v_readlane_b32 %[rb1], %[shi], %[i2s]\n\t"                             \
      "s_lshl_b64 %[l1], -2, %[i1]\n\t"      /* live beyond i1 */             \
      "v_xor_b32 %[va0], %[ra0], %[slo]\n\t"                                  \
      "v_xor_b32 %[va1], %[ra1], %[shi]\n\t"                                  \
      "v_xor_b32 %[vb0], %[rb0], %[slo]\n\t"                                  \
      "v_xor_b32 %[vb1], %[rb1], %[shi]\n\t"                                  \
      "v_bcnt_u32_b32 %[ca], %[va0], 0\n\t"                                   \
      "v_bcnt_u32_b32 %[ca], %[va1], %[ca]\n\t"                               \
      "v_bcnt_u32_b32 %[cb], %[vb0], 0\n\t"                                   \
      "v_bcnt_u32_b32 %[cb], %[vb1], %[cb]\n\t"                               \
      "v_lshl_add_u32 %[U1], %[ca], 3, %[U]\n\t"                              \
      "v_add_u32 %[U1], 0xffffff00, %[U1]\n\t"  /* U1: truth after i1 */      \
      "v_cmp_gt_i32 vcc, 0, %[U1]\n\t"          /* verify ballot */           \
      "v_lshl_add_u32 %[U], %[cb], 3, %[U1]\n\t"                              \
      "v_add_u32 %[U], 0xffffff00, %[U]\n\t"    /* U: spec after i2 */        \
      "s_and_b64 %[mm1], vcc, %[l1]\n\t"                                      \
      "s_ff1_i32_b64 %[chk], %[mm1]\n\t"                                      \
      "s_cmp_eq_u32 %[chk], %[i2]\n\t"                                        \
      "s_cselect_b32 %[tmp], %[i2], -1\n\t"                                   \
      "s_cmp_gt_i32 %[tmp], -1\n\t"          /* commit iff chk==i2>=0 */      \
      "s_cbranch_scc0 5f\n\t"                                                 \
      "s_lshl_b64 %[b1], 1, %[i2]\n\t"                                        \
      "s_or_b64 %[flips], %[flips], %[b1]\n\t"                                \
      "s_lshl_b64 %[l1], -2, %[i2]\n\t"                                       \
      "v_cmp_gt_i32 vcc, 0, %[U]\n\t"                                         \
      "s_and_b64 %[mm], vcc, %[l1]\n\t"      /* SCC = more candidates */      \
      "s_cbranch_scc1 1b\n\t"                                                 \
      "s_branch 9f\n\t"                                                       \
      "5:\n\t"                               /* mispredict / single */        \
      "v_mov_b32 %[U], %[U1]\n\t"                                             \
      "s_and_b64 %[mm], %[mm1], %[mm1]\n\t"  /* mm = mm1, SCC = (!=0) */      \
      "s_cbranch_scc1 1b\n\t"                                                 \
      "9:\n\t"                                                                \
      : [flips]"=&s"(flips), [mm]"=&s"(mm), [t]"=&s"(t_), [mm1]"=&s"(mm1),    \
        [l1]"=&s"(l1), [b1]"=&s"(b1), [i1]"=&s"(i1), [i2]"=&s"(i2),           \
        [i2s]"=&s"(i2s), [chk]"=&s"(chk), [tmp]"=&s"(tmp),                    \
        [ra0]"=&s"(ra0), [ra1]"=&s"(ra1), [rb0]"=&s"(rb0), [rb1]"=&s"(rb1),   \
        [U]"+v"(U), [U1]"=&v"(U1), [va0]"=&v"(va0), [va1]"=&v"(va1),          \
        [vb0]"=&v"(vb0), [vb1]"=&v"(vb1), [ca]"=&v"(ca), [cb]"=&v"(cb)        \
      : [slo]"v"(slo), [shi]"v"(shi)                                          \
      : "vcc", "scc");                                                        \
  }                                                                           \
  if (flips) {  /* m_p += 4·popc(flips & sigT_p) - 2·nf  (exact ints) */      \
    const int nf = (int)__popcll(flips);                                      \
    const int pc = (int)__popcll(flips & (st));                               \
    mreg += (float)(4*pc - 2*nf);                                             \
    mlds[lane] = mreg;                                                        \
  }                                                                           \
  out[rr] = ((flips >> lane) & 1ull) ? -(ss) : (ss);                          \
}

#define PREFETCH(BN, BUF, sg, st, rr, ss) {                                   \
  const float* ys = Ysw + (size_t)(BN)*4096 + lane*4;                         \
  _Pragma("unroll")                                                           \
  for (int it = 0; it < 16; ++it) glds16(ys + it*256, &(BUF)[it*256]);        \
  sg = sig[(BN)*64+lane]; st = sigT[(BN)*64+lane];                            \
  rr = perm[(BN)*64+lane]; ss = sps[(BN)*64+lane];                            \
}

__global__ __launch_bounds__(64) void hop_solve(
    const int* __restrict__ perm, const float* __restrict__ m0,
    const float* __restrict__ Ysw, const u64* __restrict__ sig,
    const u64* __restrict__ sigT, const float* __restrict__ sps,
    float* __restrict__ out)
{
  __shared__ __align__(16) float mlds[64];
  __shared__ __align__(16) float Ybuf[2][4096];
  const int lane = threadIdx.x;   // one wave; lane = row j AND pattern p
  const int ybase = lane*64, lswz = lane & 7;

  float mreg = m0[lane];
  mlds[lane] = mreg;

  u64 sgA, stA, sgB, stB; int rA, rB; float sA, sB;
  PREFETCH(0, Ybuf[0], sgA, stA, rA, sA);
  asm volatile("s_waitcnt vmcnt(0)" ::: "memory");

  for (int bb = 0; bb < NB; bb += 2) {
    PREFETCH(bb+1, Ybuf[1], sgB, stB, rB, sB);         // async, fills buf1
    PROCESS(Ybuf[0], sgA, stA, rA, sA);
    // glds(buf1) + scalar loads older than out-store: vmcnt(1) => buf1 ready
    asm volatile("s_waitcnt vmcnt(1)" ::: "memory");
    if (bb + 2 < NB) PREFETCH(bb+2, Ybuf[0], sgA, stA, rA, sA);
    PROCESS(Ybuf[1], sgB, stB, rB, sB);
    asm volatile("s_waitcnt vmcnt(1)" ::: "memory");
  }
}

extern "C" void kernel_launch(void* const* d_in, const int* in_sizes, int n_in,
                              void* d_out, int out_size, void* d_ws, size_t ws_size,
                              hipStream_t stream) {
  const float* X     = (const float*)d_in[0];
  const float* state = (const float*)d_in[1];
  const int*   perm  = (const int*)d_in[2];
  float* outp = (float*)d_out;

  float* m0  = (float*)d_ws;                 // 64 f
  float* Ysw = m0 + 64;                      // 128*4096 f
  u64*   sig = (u64*)(Ysw + 128*4096);       // 8192 u64
  u64*   sigT= sig + 8192;                   // 8192 u64
  float* sps = (float*)(sigT + 8192);        // 8192 f

  hipMemsetAsync(m0, 0, 64*sizeof(float), stream);
  hop_prep<<<dim3(NB), dim3(256), 0, stream>>>(X, state, perm, m0, Ysw, sig, sigT, sps);
  hop_solve<<<dim3(1), dim3(64), 0, stream>>>(perm, m0, Ysw, sig, sigT, sps, outp);
}

// Round 9
// 385.513 us; speedup vs baseline: 1.0553x; 1.0553x over previous
//
#include <hip/hip_runtime.h>
#include <stdint.h>

// ClassicalHopfield N=8192, P=64.  act_i·N = x_i·m - 64·s_i, m = X^T s (running).
// Blocked (64-neuron) resolve via BLOCK-LEVEL FIXED POINT:
//   serial recurrence c_j = [U_j + Sum_{i<j, c_i} d_ij < 0], d_ij = 8*popc(sig_i^sig_j)-256
//   Any self-consistent F (F == ballot(prefix-corrected U < 0)) equals the
//   serial answer (induction on lowest disagreeing j). Iterate F_0=ballot(U<0),
//   F_{n+1}=ballot(Ubar(F_n)<0); corrections are tiny vs margins so 1-3 iters;
//   incremental updates after iter 0. Non-convergence (<=6 iters) -> exact
//   serial fallback from saved U0 (rare). All small ints => exact => bit-identical.
// U_j = 2*(y_j.m) - (s_j<0) - 128; the -(s<0) implements act==0 -> +1 exactly.
// block end: m_p += 4*popc(flips & sigT_p) - 2*nf.
//
// R9: replaces the per-flip serial chain (~160cy/flip from VALU<->SALU
// dependency links, measured R5/R6/R8) with a throughput-parallel prefix
// sweep over F's set bits (independent terms, no serial chain).

#define NB 128
typedef unsigned long long u64;
typedef unsigned u32;

// ws: m0 f[64] | Ysw f[128*4096] (pre-swizzled, glds-linear layout:
//     [b][j][ (G^(j&7))*4 + c ], p=G*4+c) | sig u64[8192] | sigT u64[8192] |
//     sps f[8192]   ~2.16 MB

__device__ __forceinline__ void glds16(const void* g, void* l) {
  __builtin_amdgcn_global_load_lds(
      (const __attribute__((address_space(1))) void*)g,
      (__attribute__((address_space(3))) void*)l, 16, 0, 0);
}

__global__ __launch_bounds__(256) void hop_prep(
    const float* __restrict__ X, const float* __restrict__ state,
    const int* __restrict__ perm, float* __restrict__ m0,
    float* __restrict__ Ysw, u64* __restrict__ sig, u64* __restrict__ sigT,
    float* __restrict__ sps)
{
  const int b = blockIdx.x, t = threadIdx.x;
  const int wv = t >> 6, ln = t & 63;
  __shared__ u64 sigL[64];
  __shared__ float red[4][64];

  // single X pass: swizzled Y store + row signature + m0 partial
  float acc = 0.f;
  #pragma unroll
  for (int jj = 0; jj < 16; ++jj) {
    const int j = wv*16 + jj;                 // wave-uniform row
    const int r = perm[b*64 + j];
    const float sr = state[r];
    const float x = X[(size_t)r*64 + ln];     // coalesced 256B row
    Ysw[(size_t)b*4096 + j*64 + ((((ln >> 2) ^ (j & 7)) << 2) | (ln & 3))] = x * sr;
    u64 bb = __ballot(x < 0.f);
    if (sr < 0.f) bb = ~bb;                   // sign of y = x*sr
    if (ln == 0) { sig[b*64 + j] = bb; sigL[j] = bb; }
    acc = fmaf(x, sr, acc);
  }
  red[wv][ln] = acc;
  __syncthreads();

  // column signatures: bit i of sigT_p = bit p of sig_i
  {
    const u64 gs = sigL[ln];
    #pragma unroll
    for (int jj = 0; jj < 16; ++jj) {
      const int p = wv*16 + jj;
      u64 tb = __ballot((unsigned)((gs >> p) & 1ull));
      if (ln == 0) sigT[b*64 + p] = tb;
    }
  }

  if (t < 64) {
    atomicAdd(&m0[t], (red[0][t] + red[1][t]) + (red[2][t] + red[3][t]));
    sps[b*64 + t] = state[perm[b*64 + t]];
  }
}

// popc(sig_i ^ sig_lane) for wave-uniform i
__device__ __forceinline__ int corr_term(u32 slo, u32 shi, int i) {
  const u32 a = (u32)__builtin_amdgcn_readlane((int)slo, i);
  const u32 b = (u32)__builtin_amdgcn_readlane((int)shi, i);
  return __popc(slo ^ a) + __popc(shi ^ b);
}

__device__ __forceinline__ void process_block(
    const float* __restrict__ Yc, const u64 sg, const u64 st,
    const int rr, const float ss, float* mlds, float& mreg,
    float* __restrict__ out, const int lane, const int ybase, const int lswz)
{
  // matvec: q = y_lane . m  (swizzled conflict-free b128 reads, m broadcast)
  float q0=0.f,q1=0.f,q2=0.f,q3=0.f;
  const float4* mv4 = (const float4*)mlds;
  #pragma unroll
  for (int g = 0; g < 16; ++g) {
    const float4 yv = *(const float4*)&Yc[ybase + ((g ^ lswz) << 2)];
    const float4 mv = mv4[g];
    q0 = fmaf(yv.x, mv.x, q0); q1 = fmaf(yv.y, mv.y, q1);
    q2 = fmaf(yv.z, mv.z, q2); q3 = fmaf(yv.w, mv.w, q3);
  }
  const int U0 = (((int)((q0+q1)+(q2+q3))) << 1) - ((ss < 0.f) ? 1 : 0) - 128;
  const u32 slo = (u32)sg, shi = (u32)(sg >> 32);

  u64 F = __ballot(U0 < 0);
  u64 flips = 0ull;
  if (F) {
    int Ub = U0;
    { // full prefix application of F: Ub += Sum_{i in F, i<lane} (8*pc_i - 256)
      int acc0 = 0, acc1 = 0;
      u64 rem = F;
      while (rem) {
        const int i = (int)__builtin_ctzll(rem); rem &= rem - 1ull;
        const int pc = corr_term(slo, shi, i);
        acc0 += (lane > i) ? pc : 0;
        if (rem) {
          const int i2 = (int)__builtin_ctzll(rem); rem &= rem - 1ull;
          const int pc2 = corr_term(slo, shi, i2);
          acc1 += (lane > i2) ? pc2 : 0;
        }
      }
      const int cnt = (int)__builtin_amdgcn_mbcnt_hi(
          (u32)(F >> 32), __builtin_amdgcn_mbcnt_lo((u32)F, 0u));
      Ub += ((acc0 + acc1) << 3) - (cnt << 8);   // cnt = popc(F & below(lane))
    }
    // fixed-point refinement with incremental delta updates
    bool conv = false;
    for (int it = 0; it < 6; ++it) {
      const u64 Fn = __ballot(Ub < 0);
      if (Fn == F) { conv = true; break; }
      u64 dd = Fn ^ F;
      while (dd) {
        const int i = (int)__builtin_ctzll(dd); dd &= dd - 1ull;
        const int pc8 = (corr_term(slo, shi, i) << 3) - 256;
        const int d = ((Fn >> i) & 1ull) ? pc8 : -pc8;   // add or remove flip i
        Ub += (lane > i) ? d : 0;
      }
      F = Fn;
    }
    if (conv) {
      flips = F;        // verified fixed point == exact serial answer
    } else {
      // exact serial fallback from U0 (rare: oscillation guard)
      int Us = U0;
      u64 live = ~0ull;
      u64 mm = __ballot(Us < 0);
      while (mm) {
        const int i = (int)__builtin_ctzll(mm);
        flips |= (1ull << i);
        live = (i < 63) ? ((~0ull) << (i + 1)) : 0ull;
        Us += (corr_term(slo, shi, i) << 3) - 256;
        mm = __ballot(Us < 0) & live;
      }
    }
  }

  if (flips) {  // m_p += 4*popc(flips & sigT_p) - 2*nf  (exact ints)
    const int nf = (int)__popcll(flips);
    const int pc = (int)__popcll(flips & st);
    mreg += (float)(4*pc - 2*nf);
    mlds[lane] = mreg;
  }
  out[rr] = ((flips >> lane) & 1ull) ? -ss : ss;
}

#define PREFETCH(BN, BUF, sg, st, rr, ss) {                                   \
  const float* ys = Ysw + (size_t)(BN)*4096 + lane*4;                         \
  _Pragma("unroll")                                                           \
  for (int it = 0; it < 16; ++it) glds16(ys + it*256, &(BUF)[it*256]);        \
  sg = sig[(BN)*64+lane]; st = sigT[(BN)*64+lane];                            \
  rr = perm[(BN)*64+lane]; ss = sps[(BN)*64+lane];                            \
}

__global__ __launch_bounds__(64) void hop_solve(
    const int* __restrict__ perm, const float* __restrict__ m0,
    const float* __restrict__ Ysw, const u64* __restrict__ sig,
    const u64* __restrict__ sigT, const float* __restrict__ sps,
    float* __restrict__ out)
{
  __shared__ __align__(16) float mlds[64];
  __shared__ __align__(16) float Ybuf[2][4096];
  const int lane = threadIdx.x;   // one wave; lane = row j AND pattern p
  const int ybase = lane*64, lswz = lane & 7;

  float mreg = m0[lane];
  mlds[lane] = mreg;

  u64 sgA, stA, sgB, stB; int rA, rB; float sA, sB;
  PREFETCH(0, Ybuf[0], sgA, stA, rA, sA);
  asm volatile("s_waitcnt vmcnt(0)" ::: "memory");

  for (int bb = 0; bb < NB; bb += 2) {
    PREFETCH(bb+1, Ybuf[1], sgB, stB, rB, sB);         // async, fills buf1
    process_block(Ybuf[0], sgA, stA, rA, sA, mlds, mreg, out, lane, ybase, lswz);
    // glds(buf1) + scalar loads older than out-store: vmcnt(1) => buf1 ready
    asm volatile("s_waitcnt vmcnt(1)" ::: "memory");
    if (bb + 2 < NB) PREFETCH(bb+2, Ybuf[0], sgA, stA, rA, sA);
    process_block(Ybuf[1], sgB, stB, rB, sB, mlds, mreg, out, lane, ybase, lswz);
    asm volatile("s_waitcnt vmcnt(1)" ::: "memory");
  }
}

extern "C" void kernel_launch(void* const* d_in, const int* in_sizes, int n_in,
                              void* d_out, int out_size, void* d_ws, size_t ws_size,
                              hipStream_t stream) {
  const float* X     = (const float*)d_in[0];
  const float* state = (const float*)d_in[1];
  const int*   perm  = (const int*)d_in[2];
  float* outp = (float*)d_out;

  float* m0  = (float*)d_ws;                 // 64 f
  float* Ysw = m0 + 64;                      // 128*4096 f
  u64*   sig = (u64*)(Ysw + 128*4096);       // 8192 u64
  u64*   sigT= sig + 8192;                   // 8192 u64
  float* sps = (float*)(sigT + 8192);        // 8192 f

  hipMemsetAsync(m0, 0, 64*sizeof(float), stream);
  hop_prep<<<dim3(NB), dim3(256), 0, stream>>>(X, state, perm, m0, Ysw, sig, sigT, sps);
  hop_solve<<<dim3(1), dim3(64), 0, stream>>>(perm, m0, Ysw, sig, sigT, sps, outp);
}